// Round 2
// baseline (199.063 us; speedup 1.0000x reference)
//
#include <hip/hip_runtime.h>

// ============================================================================
// ElevationSConvResidualEncoder — reduced-form kernel (fp32 I/O).
//
// IDENTITY (holds for ALL inputs, fp32 included):
//   spk = heaviside(mem - 1.0), mem = sigmoid(o)*tanh(syn).
//   sigmoid(x) <= 1.0 and tanh(x) <= 1.0 exactly in IEEE arithmetic, so the
//   product rounds to <= 1.0, mem - 1.0 <= 0, and (mem - 1.0) > 0 is ALWAYS
//   false. reset_mechanism='none' means spk never feeds back into state, so
//   spikes === 0, pooled === 0, residual === proj_b. The 66.8 MB pooling of
//   receive_spikes and the entire 85-step ConvLSTM scan are dead code w.r.t.
//   the output.
//
// Live computation (fp32):
//   d_lat  = relu(distance @ Wd.T + bd)
//   a_lat  = relu(azimuth  @ Wa.T + ba)
//   base_e = relu(elevation@ We.T + be)
//   e_lat  = relu(base_e + 0.4*sigmoid(residual_gain) * proj_b)
//   out    = stack([d_lat, a_lat, e_lat])   -> [3, 8, 512] float32
//
// One thread per output element (12288 threads); K=256 dot in fp32 with
// float4 vector loads (rows are 1 KB, 16B-aligned).
// ============================================================================

#define B_    8
#define HID_  512
#define KDIM_ 256
#define TOTAL_ (3 * B_ * HID_)

__global__ __launch_bounds__(256) void encoder_reduced_f32_kernel(
    const float* __restrict__ dist,
    const float* __restrict__ az,
    const float* __restrict__ elev,
    const float* __restrict__ Wd, const float* __restrict__ bd,
    const float* __restrict__ Wa, const float* __restrict__ ba,
    const float* __restrict__ We, const float* __restrict__ be,
    const float* __restrict__ proj_b,
    const float* __restrict__ rgain,
    float* __restrict__ out)
{
    int idx = blockIdx.x * 256 + threadIdx.x;
    if (idx >= TOTAL_) return;
    int s = idx >> 12;          // 0: distance, 1: azimuth, 2: elevation
    int r = idx & 4095;
    int b = r >> 9;             // batch 0..7
    int h = r & 511;            // hidden unit 0..511

    const float* x = (s == 0 ? dist : (s == 1 ? az : elev)) + b * KDIM_;
    const float* W = (s == 0 ? Wd   : (s == 1 ? Wa : We))   + (size_t)h * KDIM_;
    const float* bias = (s == 0 ? bd : (s == 1 ? ba : be));

    const float4* W4 = (const float4*)W;   // 256 fp32 = 1 KB rows, 16B-aligned
    const float4* x4 = (const float4*)x;

    float acc = 0.f;
#pragma unroll
    for (int k = 0; k < KDIM_ / 4; ++k) {
        float4 wv = W4[k];
        float4 xv = x4[k];
        acc = fmaf(wv.x, xv.x, acc);
        acc = fmaf(wv.y, xv.y, acc);
        acc = fmaf(wv.z, xv.z, acc);
        acc = fmaf(wv.w, xv.w, acc);
    }

    float v = fmaxf(acc + bias[h], 0.f);   // relu(x @ W.T + b)

    if (s == 2) {
        // e_lat = relu(base_e + 0.4*sigmoid(residual_gain)*(pooled@projW.T + proj_b))
        // pooled === 0 (identity above) => residual = proj_b[h].
        float g = rgain[0];
        float scale = 0.4f / (1.f + __expf(-g));
        v = fmaxf(v + scale * proj_b[h], 0.f);
    }

    out[idx] = v;
}

extern "C" void kernel_launch(void* const* d_in, const int* in_sizes, int n_in,
                              void* d_out, int out_size, void* d_ws, size_t ws_size,
                              hipStream_t stream) {
    (void)in_sizes; (void)n_in; (void)d_ws; (void)ws_size; (void)out_size;
    // setup_inputs() order:
    //  0 distance [8,256]   1 azimuth [8,256]   2 elevation [8,256]
    //  3 receive_spikes [8,64,64,1020] (dead)   4 spike_count [8] int32 (unused)
    //  5 Wd [512,256]  6 bd [512]  7 Wa [512,256]  8 ba [512]
    //  9 We [512,256] 10 be [512]
    // 11 conv_W (dead) 12 conv_b (dead) 13 proj_W (dead: pooled==0)
    // 14 proj_b [512] 15 residual_gain [1]
    const float* dist = (const float*)d_in[0];
    const float* az   = (const float*)d_in[1];
    const float* elev = (const float*)d_in[2];
    const float* Wd   = (const float*)d_in[5];
    const float* bd   = (const float*)d_in[6];
    const float* Wa   = (const float*)d_in[7];
    const float* ba   = (const float*)d_in[8];
    const float* We   = (const float*)d_in[9];
    const float* be   = (const float*)d_in[10];
    const float* pb   = (const float*)d_in[14];
    const float* rg   = (const float*)d_in[15];
    float* out = (float*)d_out;

    encoder_reduced_f32_kernel<<<dim3((TOTAL_ + 255) / 256), dim3(256), 0, stream>>>(
        dist, az, elev, Wd, bd, Wa, ba, We, be, pb, rg, out);
}